// Round 3
// baseline (5521.558 us; speedup 1.0000x reference)
//
#include <hip/hip_runtime.h>
#include <hip/hip_bf16.h>
#include <stdint.h>

#define N_NODES 25600
#define N_EDGES 51200
#define NG      512

typedef __attribute__((ext_vector_type(4))) float f32x4;
typedef __attribute__((ext_vector_type(8))) short bf16x8;

__device__ __forceinline__ float lrelu(float v){ return v > 0.f ? v : 0.01f*v; }
__device__ __forceinline__ float sigm(float v){ return 1.f/(1.f+__expf(-v)); }
__device__ __forceinline__ unsigned short f2b(float v){
  union { float f; uint32_t u; } x; x.f = v;
  uint32_t u = x.u;
  return (unsigned short)((u + 0x7FFFu + ((u>>16)&1u)) >> 16);
}

// ---------------- prep: W2 permute->bf16 + weight transposes ----------------
// W2bT[o][c*128 + d*2 + kl] = net2_w[(d*64+o)*128 + (c*2+kl)]   (o<64, K'=8192)
__global__ void k_prep(const float* __restrict__ net2_w, unsigned short* __restrict__ W2bT,
                       const float* __restrict__ gwih, const float* __restrict__ gwhh,
                       float* __restrict__ gwihT, float* __restrict__ gwhhT,
                       const float* __restrict__ lwih, const float* __restrict__ lwhh,
                       float* __restrict__ lwihT, float* __restrict__ lwhhT,
                       const float* __restrict__ lin1w, float* __restrict__ l1T,
                       const float* __restrict__ lin2w, float* __restrict__ l2T,
                       const float* __restrict__ lin0w, float* __restrict__ l0T) {
  const int total = 524288+12288+12288+32768+16384+32768+53760+1536;
  for (int i = blockIdx.x*blockDim.x + threadIdx.x; i < total; i += gridDim.x*blockDim.x) {
    int idx = i;
    if (idx < 524288) {
      int o = idx >> 13, rem = idx & 8191;
      int c = rem >> 7, r2 = rem & 127;
      int d = r2 >> 1, kl = r2 & 1;
      W2bT[idx] = f2b(net2_w[(d*64+o)*128 + (c*2+kl)]);
      continue;
    }
    idx -= 524288;
    if (idx < 12288) { int d = idx/192, j = idx%192; gwihT[idx] = gwih[j*64+d]; continue; }
    idx -= 12288;
    if (idx < 12288) { int d = idx/192, j = idx%192; gwhhT[idx] = gwhh[j*64+d]; continue; }
    idx -= 12288;
    if (idx < 32768) { int c = idx/256, j = idx%256; lwihT[idx] = lwih[j*128+c]; continue; }
    idx -= 32768;
    if (idx < 16384) { int d = idx/256, j = idx%256; lwhhT[idx] = lwhh[j*64+d]; continue; }
    idx -= 16384;
    if (idx < 32768) { int d = idx/512, j = idx%512; l1T[idx] = lin1w[j*64+d]; continue; }
    idx -= 32768;
    if (idx < 53760) { int j = idx/105, o = idx%105; l2T[idx] = lin2w[o*512+j]; continue; }
    idx -= 53760;
    { int f = idx/64, o = idx%64; l0T[idx] = lin0w[o*24+f]; }
  }
}

// ---------------- lin0: out = lrelu(x @ lin0_w.T + b); Q0 = out @ b2mat ----------------
__global__ __launch_bounds__(256) void k_lin0(const float* __restrict__ x, const float* __restrict__ l0T,
     const float* __restrict__ b, const float* __restrict__ net2_b,
     float* __restrict__ outf, float* __restrict__ Q) {
  int t = threadIdx.x & 63;
  int n = blockIdx.x*4 + (threadIdx.x>>6);
  float xv = (t < 24) ? x[n*24+t] : 0.f;
  float acc = b[t];
  #pragma unroll
  for (int f = 0; f < 24; ++f) acc += __shfl(xv, f) * l0T[f*64+t];
  acc = lrelu(acc);
  outf[n*64+t] = acc;
  float qa = 0.f;
  #pragma unroll 8
  for (int d = 0; d < 64; ++d) qa += __shfl(acc, d) * net2_b[d*64+t];
  Q[n*64+t] = qa;
}

// ---------------- eh = lrelu(edge_attr @ net1_w.T + b) (f32) ----------------
__global__ __launch_bounds__(256) void k_eh(const float* __restrict__ ea, const float* __restrict__ w,
    const float* __restrict__ b, float* __restrict__ eh) {
  int i = blockIdx.x*256 + threadIdx.x;     // E*128 exact
  int e = i >> 7, k = i & 127;
  float4 a = *(const float4*)(ea + e*4);
  float4 ww = *(const float4*)(w + k*4);
  float v = a.x*ww.x + a.y*ww.y + a.z*ww.z + a.w*ww.w + b[k];
  eh[i] = lrelu(v);
}

// ---------------- deterministic per-graph CSR by dst ----------------
__global__ __launch_bounds__(128) void k_csr(const int* __restrict__ ei, int* __restrict__ deg,
                                             int* __restrict__ off, int* __restrict__ csr) {
  __shared__ int cnt[50];
  __shared__ int cur[50];
  __shared__ int dloc[100];
  int g = blockIdx.x, t = threadIdx.x;
  const int* dst = ei + N_EDGES;
  if (t < 50) cnt[t] = 0;
  __syncthreads();
  if (t < 100) { dloc[t] = dst[g*100+t] - g*50; atomicAdd(&cnt[dloc[t]], 1); }
  __syncthreads();
  if (t == 0) { int run = 0; for (int i = 0; i < 50; ++i) { cur[i] = run; run += cnt[i]; } }
  __syncthreads();
  if (t < 50) { deg[g*50+t] = cnt[t]; off[g*50+t] = g*100 + cur[t]; }
  __syncthreads();
  if (t < 100) {
    int p = 0, me = dloc[t];
    for (int i = 0; i < t; ++i) p += (dloc[i] == me);   // deterministic rank
    csr[g*100 + cur[me] + p] = g*100 + t;
  }
}

// ---------------- per-step fused bilinear: agg[v,o] = sum_{e->v} x_src (x) eh : W2  + Q[src,o]
// 2 graphs per block; P rebuilt per K-chunk in LDS (bf16), MFMA vs W2bT (L2).
__global__ __launch_bounds__(512) void k_bilin(const float* __restrict__ outf,
    const float* __restrict__ eh, const unsigned short* __restrict__ W2bT,
    const float* __restrict__ Q, const int* __restrict__ ei,
    const int* __restrict__ csr, const int* __restrict__ offs, const int* __restrict__ deg,
    float* __restrict__ agg) {
  __shared__ unsigned short A_lds[128*128];   // 32KB, XOR-swizzled 16B slots
  __shared__ float xl[100*64];                // 25.6KB pair-local node features
  __shared__ float ehl[2][400];               // dbuf k-pair slices of eh
  __shared__ int   offl[128];
  __shared__ int   degl[128];
  __shared__ short srcl[200];                 // csr-ordered src (pair-local 0..99)
  __shared__ short elcl[200];                 // csr-ordered edge (pair-local 0..199)
  int tid = threadIdx.x;
  int bid = blockIdx.x;                       // graphs 2*bid, 2*bid+1
  char* Ab = (char*)A_lds;

  // ---- stage meta + x ----
  if (tid < 128) {
    int g = tid >> 6, v = tid & 63;
    if (v < 50) { int gn = (bid*2+g)*50 + v; offl[tid] = offs[gn] - bid*200; degl[tid] = deg[gn]; }
    else { offl[tid] = 0; degl[tid] = 0; }
  }
  if (tid < 200) {
    int eg = csr[bid*200 + tid];
    elcl[tid] = (short)(eg - bid*200);
    srcl[tid] = (short)(ei[eg] - bid*100);
  }
  for (int i = tid; i < 6400; i += 512) xl[i] = outf[bid*6400 + i];
  if (tid < 400) {               // prestage chunk 0 eh slice: [edge j][kl]
    int j = tid >> 1, kl = tid & 1;
    ehl[0][tid] = eh[(bid*200 + j)*128 + kl];
  }
  __syncthreads();

  int wave = tid >> 6, lane = tid & 63;
  int mg = wave >> 2, nn = wave & 3;          // wave grid: 2 m-groups x 4 n-tiles
  int q = lane >> 4, cc = lane & 15;
  f32x4 acc[4] = {};

  for (int c = 0; c < 64; ++c) {
    int b = c & 1;
    // B-frags for this chunk (issue early; lands during P-build)
    const unsigned short* Bp = W2bT + (size_t)(nn*16+cc)*8192 + c*128 + q*8;
    bf16x8 bf0 = *(const bf16x8*)(Bp);
    bf16x8 bf1 = *(const bf16x8*)(Bp + 32);
    bf16x8 bf2 = *(const bf16x8*)(Bp + 64);
    bf16x8 bf3 = *(const bf16x8*)(Bp + 96);
    // P-build: task (r,d) -> A[r][d*2 + {0,1}]
    #pragma unroll
    for (int rr = 0; rr < 16; ++rr) {
      int tau = tid + rr*512;
      int r = tau >> 6, d = tau & 63;
      int o0 = offl[r], dg = degl[r];
      float p0 = 0.f, p1 = 0.f;
      for (int ii = 0; ii < dg; ++ii) {
        int j = o0 + ii;
        float xv = xl[srcl[j]*64 + d];
        p0 += xv * ehl[b][elcl[j]*2];
        p1 += xv * ehl[b][elcl[j]*2 + 1];
      }
      unsigned int w = (unsigned int)f2b(p0) | ((unsigned int)f2b(p1) << 16);
      *(unsigned int*)(Ab + r*256 + (((d>>2) ^ (r&7)) << 4) + ((d&3) << 2)) = w;
    }
    // stage next chunk's eh slice (other buffer)
    if (c + 1 < 64 && tid < 400) {
      int j = tid >> 1, kl = tid & 1;
      ehl[b^1][tid] = eh[(bid*200 + j)*128 + (c+1)*2 + kl];
    }
    __syncthreads();
    // MFMA: 4 ksteps x 4 m-tiles
    #pragma unroll
    for (int ks = 0; ks < 4; ++ks) {
      bf16x8 bfr = (ks==0) ? bf0 : (ks==1) ? bf1 : (ks==2) ? bf2 : bf3;
      #pragma unroll
      for (int mi = 0; mi < 4; ++mi) {
        int row = mg*64 + mi*16 + cc;
        int slot = (ks*4 + q) ^ (row & 7);
        bf16x8 af = *(const bf16x8*)(Ab + row*256 + slot*16);
        acc[mi] = __builtin_amdgcn_mfma_f32_16x16x32_bf16(af, bfr, acc[mi], 0, 0, 0);
      }
    }
    __syncthreads();
  }

  // epilogue: + Q-gather, write agg
  #pragma unroll
  for (int mi = 0; mi < 4; ++mi) {
    #pragma unroll
    for (int i2 = 0; i2 < 4; ++i2) {
      int r = mg*64 + mi*16 + q*4 + i2;
      int v = r & 63;
      if (v < 50) {
        int g = r >> 6;
        int o = nn*16 + cc;
        float val = acc[mi][i2];
        int o0 = offl[r], dg = degl[r];
        for (int ii = 0; ii < dg; ++ii)
          val += Q[(bid*100 + srcl[o0+ii])*64 + o];
        agg[(bid*100 + g*50 + v)*64 + o] = val;
      }
    }
  }
}

// ---------------- per-step: NNConv root + bias + GRU cell (f32) + Q for next step ----------------
__global__ __launch_bounds__(256) void k_upd(float* __restrict__ outf,
    const float* __restrict__ agg, const int* __restrict__ deg,
    const float* __restrict__ root_w, const float* __restrict__ conv_b,
    const float* __restrict__ wihT, const float* __restrict__ whhT,
    const float* __restrict__ bih, const float* __restrict__ bhh,
    const float* __restrict__ net2_b, float* __restrict__ Q) {
  int t = threadIdx.x & 63;
  int n = blockIdx.x*4 + (threadIdx.x>>6);
  float ot = outf[n*64+t];
  int dgi = deg[n];
  float av = agg[n*64+t] * (1.f / (float)(dgi > 0 ? dgi : 1));
  float racc = 0.f;
  #pragma unroll 8
  for (int d = 0; d < 64; ++d) racc += __shfl(ot, d) * root_w[d*64+t];
  float m = lrelu(av + racc + conv_b[t]);
  float gi0 = bih[t], gi1 = bih[64+t], gi2 = bih[128+t];
  float gh0 = bhh[t], gh1 = bhh[64+t], gh2 = bhh[128+t];
  #pragma unroll 4
  for (int d = 0; d < 64; ++d) {
    float md = __shfl(m, d), od = __shfl(ot, d);
    const float* Li = wihT + d*192 + t;
    const float* Lh = whhT + d*192 + t;
    gi0 += md*Li[0];  gi1 += md*Li[64];  gi2 += md*Li[128];
    gh0 += od*Lh[0];  gh1 += od*Lh[64];  gh2 += od*Lh[128];
  }
  float r = sigm(gi0+gh0), z = sigm(gi1+gh1);
  float nn = tanhf(gi2 + r*gh2);
  float h = (1.f - z)*nn + z*ot;
  outf[n*64+t] = h;
  float qa = 0.f;
  #pragma unroll 8
  for (int d = 0; d < 64; ++d) qa += __shfl(h, d) * net2_b[d*64+t];
  Q[n*64+t] = qa;
}

// ---------------- per-stem head ----------------
__global__ __launch_bounds__(256) void k_stem(const float* __restrict__ outf,
    const int* __restrict__ stems, const int* __restrict__ stems_batch,
    const float* __restrict__ l1T, const float* __restrict__ l1b,
    const float* __restrict__ l2T, const float* __restrict__ l2b,
    float* __restrict__ per_stem) {
  int t = threadIdx.x & 63;
  int s = blockIdx.x*4 + (threadIdx.x>>6);
  int node = stems_batch[s]*50 + stems[s];
  float sx = outf[node*64+t];
  float t1[8];
  #pragma unroll
  for (int g = 0; g < 8; ++g) t1[g] = l1b[g*64+t];
  for (int d = 0; d < 64; ++d) {
    float xd = __shfl(sx, d);
    const float* L = l1T + d*512 + t;
    #pragma unroll
    for (int g = 0; g < 8; ++g) t1[g] += xd * L[g*64];
  }
  #pragma unroll
  for (int g = 0; g < 8; ++g) t1[g] = lrelu(t1[g]);
  float a0 = l2b[t];
  float a1 = (t < 41) ? l2b[64+t] : 0.f;
  for (int g = 0; g < 8; ++g) {
    for (int d = 0; d < 64; ++d) {
      float tj = __shfl(t1[g], d);
      int j = g*64 + d;
      a0 += tj * l2T[j*105 + t];
      a1 += tj * ((t < 41) ? l2T[j*105 + 64 + t] : 0.f);
    }
  }
  per_stem[s*105 + t] = a0;
  if (t < 41) per_stem[s*105 + 64 + t] = a1;
}

// ---------------- Set2Set (3 LSTM-attention steps) + final linear ----------------
__global__ __launch_bounds__(64) void k_s2s(const float* __restrict__ outf,
    const float* __restrict__ wihT, const float* __restrict__ whhT,
    const float* __restrict__ bih, const float* __restrict__ bhh,
    const float* __restrict__ l3w, const float* __restrict__ l3b,
    float* __restrict__ sout) {
  int b = blockIdx.x, t = threadIdx.x;
  const float* og = outf + b*50*64;
  float qlo = 0.f, qhi = 0.f, hs = 0.f, cs = 0.f;
  float b0 = bih[t]+bhh[t], b1 = bih[64+t]+bhh[64+t], b2 = bih[128+t]+bhh[128+t], b3 = bih[192+t]+bhh[192+t];
  for (int it = 0; it < 3; ++it) {
    float g0 = b0, g1 = b1, g2 = b2, g3 = b3;
    for (int c = 0; c < 64; ++c) {
      float qc = __shfl(qlo, c);
      const float* L = wihT + c*256 + t;
      g0 += qc*L[0]; g1 += qc*L[64]; g2 += qc*L[128]; g3 += qc*L[192];
    }
    for (int c = 0; c < 64; ++c) {
      float qc = __shfl(qhi, c);
      const float* L = wihT + (64+c)*256 + t;
      g0 += qc*L[0]; g1 += qc*L[64]; g2 += qc*L[128]; g3 += qc*L[192];
    }
    for (int d = 0; d < 64; ++d) {
      float hd = __shfl(hs, d);
      const float* L = whhT + d*256 + t;
      g0 += hd*L[0]; g1 += hd*L[64]; g2 += hd*L[128]; g3 += hd*L[192];
    }
    float ig = sigm(g0), fg = sigm(g1), cg = tanhf(g2), oo = sigm(g3);
    cs = fg*cs + ig*cg;
    hs = oo*tanhf(cs);
    float ei = -3.4e38f;
    for (int i = 0; i < 50; ++i) {
      float p = og[i*64+t]*hs;
      #pragma unroll
      for (int m2 = 1; m2 < 64; m2 <<= 1) p += __shfl_xor(p, m2);
      if (t == i) ei = p;
    }
    float em = ei;
    #pragma unroll
    for (int m2 = 1; m2 < 64; m2 <<= 1) em = fmaxf(em, __shfl_xor(em, m2));
    float av = (t < 50) ? __expf(ei - em) : 0.f;
    float as = av;
    #pragma unroll
    for (int m2 = 1; m2 < 64; m2 <<= 1) as += __shfl_xor(as, m2);
    av /= as;
    float rr = 0.f;
    for (int i = 0; i < 50; ++i) rr += __shfl(av, i) * og[i*64+t];
    qlo = hs; qhi = rr;
  }
  float p = qlo*l3w[t] + qhi*l3w[64+t];
  #pragma unroll
  for (int m2 = 1; m2 < 64; m2 <<= 1) p += __shfl_xor(p, m2);
  if (t == 0) sout[b] = p + l3b[0];
}

extern "C" void kernel_launch(void* const* d_in, const int* in_sizes, int n_in,
                              void* d_out, int out_size, void* d_ws, size_t ws_size,
                              hipStream_t stream) {
  const float* x          = (const float*)d_in[0];
  const float* edge_attr  = (const float*)d_in[1];
  const int*   edge_index = (const int*)  d_in[2];
  const int*   stems      = (const int*)  d_in[4];
  const int*   stems_b    = (const int*)  d_in[5];
  const float* lin0_w = (const float*)d_in[6];
  const float* lin0_b = (const float*)d_in[7];
  const float* net1_w = (const float*)d_in[8];
  const float* net1_b = (const float*)d_in[9];
  const float* net2_w = (const float*)d_in[10];
  const float* net2_b = (const float*)d_in[11];
  const float* root_w = (const float*)d_in[12];
  const float* conv_b = (const float*)d_in[13];
  const float* gru_wih = (const float*)d_in[14];
  const float* gru_whh = (const float*)d_in[15];
  const float* gru_bih = (const float*)d_in[16];
  const float* gru_bhh = (const float*)d_in[17];
  const float* lin1_w = (const float*)d_in[18];
  const float* lin1_b = (const float*)d_in[19];
  const float* lin2_w = (const float*)d_in[20];
  const float* lin2_b = (const float*)d_in[21];
  const float* lstm_wih = (const float*)d_in[22];
  const float* lstm_whh = (const float*)d_in[23];
  const float* lstm_bih = (const float*)d_in[24];
  const float* lstm_bhh = (const float*)d_in[25];
  const float* lin3_w = (const float*)d_in[26];
  const float* lin3_b = (const float*)d_in[27];

  char* ws = (char*)d_ws;
  size_t off = 0;
  auto alloc = [&](size_t bytes) { void* p = ws + off; off += (bytes + 255) & ~(size_t)255; return p; };
  float* ehf  = (float*)alloc((size_t)N_EDGES*128*4);          // 26.2MB
  unsigned short* W2bT = (unsigned short*)alloc(524288*2);     // 1MB
  float* outf = (float*)alloc((size_t)N_NODES*64*4);           // 6.5MB
  float* agg  = (float*)alloc((size_t)N_NODES*64*4);           // 6.5MB
  float* Qb   = (float*)alloc((size_t)N_NODES*64*4);           // 6.5MB
  int* deg  = (int*)alloc(N_NODES*4);
  int* offs = (int*)alloc(N_NODES*4);
  int* csr  = (int*)alloc(N_EDGES*4);
  float* gwihT = (float*)alloc(12288*4);
  float* gwhhT = (float*)alloc(12288*4);
  float* lwihT = (float*)alloc(32768*4);
  float* lwhhT = (float*)alloc(16384*4);
  float* l1T   = (float*)alloc(32768*4);
  float* l2T   = (float*)alloc(53760*4);
  float* l0T   = (float*)alloc(1536*4);

  if (off > ws_size) {   // diagnosable fallback: zero output (signature absmax 1.5625e-1)
    hipMemsetAsync(d_out, 0, (size_t)out_size * sizeof(float), stream);
    return;
  }

  float* per_stem = (float*)d_out;
  float* sout = per_stem + 2560*105;

  k_prep<<<2680, 256, 0, stream>>>(net2_w, W2bT, gru_wih, gru_whh, gwihT, gwhhT,
                                   lstm_wih, lstm_whh, lwihT, lwhhT,
                                   lin1_w, l1T, lin2_w, l2T, lin0_w, l0T);
  k_lin0<<<N_NODES/4, 256, 0, stream>>>(x, l0T, lin0_b, net2_b, outf, Qb);
  k_eh<<<N_EDGES*128/256, 256, 0, stream>>>(edge_attr, net1_w, net1_b, ehf);
  k_csr<<<NG, 128, 0, stream>>>(edge_index, deg, offs, csr);
  for (int s = 0; s < 12; ++s) {
    k_bilin<<<NG/2, 512, 0, stream>>>(outf, ehf, W2bT, Qb, edge_index, csr, offs, deg, agg);
    k_upd<<<N_NODES/4, 256, 0, stream>>>(outf, agg, deg, root_w, conv_b,
                                         gwihT, gwhhT, gru_bih, gru_bhh, net2_b, Qb);
  }
  k_stem<<<2560/4, 256, 0, stream>>>(outf, stems, stems_b, l1T, lin1_b, l2T, lin2_b, per_stem);
  k_s2s<<<NG, 64, 0, stream>>>(outf, lwihT, lwhhT, lstm_bih, lstm_bhh, lin3_w, lin3_b, sout);
}

// Round 4
// 2621.589 us; speedup vs baseline: 2.1062x; 2.1062x over previous
//
#include <hip/hip_runtime.h>
#include <hip/hip_bf16.h>
#include <stdint.h>

#define N_NODES 25600
#define N_EDGES 51200
#define NG      512
#define XSTR    76

typedef __attribute__((ext_vector_type(4))) float f32x4;
typedef __attribute__((ext_vector_type(2))) float f32x2;
typedef __attribute__((ext_vector_type(8))) short bf16x8;

__device__ __forceinline__ float lrelu(float v){ return v > 0.f ? v : 0.01f*v; }
__device__ __forceinline__ float sigm(float v){ return 1.f/(1.f+__expf(-v)); }
__device__ __forceinline__ unsigned short f2b(float v){
  union { float f; uint32_t u; } x; x.f = v;
  uint32_t u = x.u;
  return (unsigned short)((u + 0x7FFFu + ((u>>16)&1u)) >> 16);
}
__device__ __forceinline__ unsigned int pk2(float a, float b){
  unsigned int r;
  asm("v_cvt_pk_bf16_f32 %0, %1, %2" : "=v"(r) : "v"(a), "v"(b));
  return r;
}
__device__ __forceinline__ float rl(float v, int l){
  return __int_as_float(__builtin_amdgcn_readlane(__float_as_int(v), l));
}

// ---------------- prep: W2 permute->bf16 + packed GRU weights + transposes ----------------
// W2bT[o][c*128 + d*2 + kl] = net2_w[(d*64+o)*128 + (c*2+kl)]
// gw6[(d*64+t)*8 + j] : j=0..2 gru_wih rows (r,z,n) col d; j=3..5 gru_whh; j=6,7 pad
__global__ void k_prep(const float* __restrict__ net2_w, unsigned short* __restrict__ W2bT,
                       const float* __restrict__ gwih, const float* __restrict__ gwhh,
                       float* __restrict__ gw6,
                       const float* __restrict__ lwih, const float* __restrict__ lwhh,
                       float* __restrict__ lwihT, float* __restrict__ lwhhT,
                       const float* __restrict__ lin1w, float* __restrict__ l1T,
                       const float* __restrict__ lin2w, float* __restrict__ l2T,
                       const float* __restrict__ lin0w, float* __restrict__ l0T) {
  const int total = 524288+32768+32768+16384+32768+53760+1536;
  for (int i = blockIdx.x*blockDim.x + threadIdx.x; i < total; i += gridDim.x*blockDim.x) {
    int idx = i;
    if (idx < 524288) {
      int o = idx >> 13, rem = idx & 8191;
      int c = rem >> 7, r2 = rem & 127;
      int d = r2 >> 1, kl = r2 & 1;
      W2bT[idx] = f2b(net2_w[(d*64+o)*128 + (c*2+kl)]);
      continue;
    }
    idx -= 524288;
    if (idx < 32768) {
      int dt = idx >> 3, j = idx & 7;
      int d = dt >> 6, t = dt & 63;
      float v = 0.f;
      if (j < 3) v = gwih[(j*64+t)*64 + d];
      else if (j < 6) v = gwhh[((j-3)*64+t)*64 + d];
      gw6[idx] = v; continue;
    }
    idx -= 32768;
    if (idx < 32768) { int c = idx/256, j = idx%256; lwihT[idx] = lwih[j*128+c]; continue; }
    idx -= 32768;
    if (idx < 16384) { int d = idx/256, j = idx%256; lwhhT[idx] = lwhh[j*64+d]; continue; }
    idx -= 16384;
    if (idx < 32768) { int d = idx/512, j = idx%512; l1T[idx] = lin1w[j*64+d]; continue; }
    idx -= 32768;
    if (idx < 53760) { int j = idx/105, o = idx%105; l2T[idx] = lin2w[o*512+j]; continue; }
    idx -= 53760;
    { int f = idx/64, o = idx%64; l0T[idx] = lin0w[o*24+f]; }
  }
}

// ---------------- lin0: out = lrelu(x @ lin0_w.T + b); Q0 = out @ b2mat ----------------
__global__ __launch_bounds__(256) void k_lin0(const float* __restrict__ x, const float* __restrict__ l0T,
     const float* __restrict__ b, const float* __restrict__ net2_b,
     float* __restrict__ outf, float* __restrict__ Q) {
  int t = threadIdx.x & 63;
  int n = blockIdx.x*4 + (threadIdx.x>>6);
  float xv = (t < 24) ? x[n*24+t] : 0.f;
  float acc = b[t];
  #pragma unroll
  for (int f = 0; f < 24; ++f) acc += __shfl(xv, f) * l0T[f*64+t];
  acc = lrelu(acc);
  outf[n*64+t] = acc;
  float qa = 0.f;
  #pragma unroll 8
  for (int d = 0; d < 64; ++d) qa += __shfl(acc, d) * net2_b[d*64+t];
  Q[n*64+t] = qa;
}

// ---------------- ehT[k][e] = lrelu(edge_attr @ net1_w.T + b), transposed via LDS ----------------
__global__ __launch_bounds__(256) void k_eh(const float* __restrict__ ea, const float* __restrict__ w,
    const float* __restrict__ b, float* __restrict__ ehT) {
  __shared__ float tile[128][65];
  int e0 = blockIdx.x*64;
  int tid = threadIdx.x;
  #pragma unroll
  for (int r = 0; r < 32; ++r) {
    int idx = tid + r*256; int el = idx >> 7, k = idx & 127;
    float4 a = *(const float4*)(ea + (size_t)(e0+el)*4);
    float4 ww = *(const float4*)(w + k*4);
    tile[k][el] = lrelu(a.x*ww.x + a.y*ww.y + a.z*ww.z + a.w*ww.w + b[k]);
  }
  __syncthreads();
  #pragma unroll
  for (int r = 0; r < 32; ++r) {
    int idx = tid + r*256; int k = idx >> 6, el = idx & 63;
    ehT[(size_t)k*N_EDGES + e0 + el] = tile[k][el];
  }
}

// ---------------- deterministic per-graph CSR by dst ----------------
__global__ __launch_bounds__(128) void k_csr(const int* __restrict__ ei, int* __restrict__ deg,
                                             int* __restrict__ off, int* __restrict__ csr) {
  __shared__ int cnt[50];
  __shared__ int cur[50];
  __shared__ int dloc[100];
  int g = blockIdx.x, t = threadIdx.x;
  const int* dst = ei + N_EDGES;
  if (t < 50) cnt[t] = 0;
  __syncthreads();
  if (t < 100) { dloc[t] = dst[g*100+t] - g*50; atomicAdd(&cnt[dloc[t]], 1); }
  __syncthreads();
  if (t == 0) { int run = 0; for (int i = 0; i < 50; ++i) { cur[i] = run; run += cnt[i]; } }
  __syncthreads();
  if (t < 50) { deg[g*50+t] = cnt[t]; off[g*50+t] = g*100 + cur[t]; }
  __syncthreads();
  if (t < 100) {
    int p = 0, me = dloc[t];
    for (int i = 0; i < t; ++i) p += (dloc[i] == me);   // deterministic rank
    csr[g*100 + cur[me] + p] = g*100 + t;
  }
}

// ---------------- per-step fused bilinear, 1 graph/block ----------------
// agg[v,o] = sum_{e->v} [ sum_{d,k} x[src,d] eh[e,k] W2[(d,o),k] + Q[src,o] ]
__global__ __launch_bounds__(512) void k_bilin(const float* __restrict__ outf,
    const float* __restrict__ ehT, const unsigned short* __restrict__ W2bT,
    const float* __restrict__ Q, const int* __restrict__ ei,
    const int* __restrict__ csr, const int* __restrict__ offs, const int* __restrict__ deg,
    float* __restrict__ agg) {
  __shared__ __align__(16) unsigned short A_lds[64*128];   // 16 KB, swizzled 16B slots
  __shared__ __align__(16) unsigned short B_lds[64*128];   // 16 KB, swizzled
  __shared__ __align__(16) float xl[50*XSTR];              // 15.2 KB node feats (stride 76)
  __shared__ __align__(16) float ehl[256];                 // [edge*2 + kl] chunk eh slice
  __shared__ int sel[100];                                 // src | (elc<<16)
  __shared__ int offl[64], degl[64];
  int tid = threadIdx.x;
  int g = blockIdx.x;
  char* Ab = (char*)A_lds;
  char* Bb = (char*)B_lds;

  // ---- prologue staging ----
  if (tid < 64) {
    if (tid < 50) { offl[tid] = offs[g*50+tid] - g*100; degl[tid] = deg[g*50+tid]; }
    else { offl[tid] = 0; degl[tid] = 0; }
  }
  if (tid < 100) {
    int eg = csr[g*100 + tid];
    sel[tid] = (ei[eg] - g*50) | ((eg - g*100) << 16);
  }
  for (int i = tid; i < 3200; i += 512) xl[(i>>6)*XSTR + (i&63)] = outf[g*3200 + i];
  int sj = tid >> 1, skl = tid & 1;
  if (tid < 256 && sj < 100)
    ehl[sj*2+skl] = ehT[(size_t)skl*N_EDGES + g*100 + sj];
  // B staging assignment: o-row o_s, 16 k' per thread
  int o_s = tid >> 3, j2 = tid & 7;
  int4 br0, br1;
  { const unsigned short* W2 = W2bT + (size_t)o_s*8192 + j2*16;
    br0 = *(const int4*)(W2); br1 = *(const int4*)(W2 + 8); }
  __syncthreads();

  // y-build binding: row r (node), 8 d-values
  int r = tid >> 3, dq = tid & 7, d0 = dq*8;
  int myo = offl[r], mydg = degl[r];
  uint abase = (uint)r*256u, r7 = (uint)(r & 7);
  uint bbase = (uint)o_s*256u, o7 = (uint)(o_s & 7);
  int wave = tid >> 6, lane = tid & 63;
  int nn = wave & 3, mh = wave >> 2;
  int ql = lane >> 4, cc = lane & 15;
  f32x4 acc0 = {0,0,0,0}, acc1 = {0,0,0,0};

  for (int c = 0; c < 64; ++c) {
    // issue next-chunk eh slice (global, lands during compute)
    float ereg = 0.f;
    if (c < 63 && tid < 256 && sj < 100)
      ereg = ehT[(size_t)(2*(c+1)+skl)*N_EDGES + g*100 + sj];
    __syncthreads();                       // A: prev MFMA done reading A/B
    // write B tile for THIS chunk (regs loaded last chunk)
    *(int4*)(Bb + bbase + (((uint)(j2*2  ) ^ o7) << 4)) = br0;
    *(int4*)(Bb + bbase + (((uint)(j2*2+1) ^ o7) << 4)) = br1;
    // y-build A tile
    if (mydg > 0) {
      f32x2 pp0 = {0,0}, pp1 = {0,0}, pp2 = {0,0}, pp3 = {0,0};
      f32x2 pp4 = {0,0}, pp5 = {0,0}, pp6 = {0,0}, pp7 = {0,0};
      for (int ii = 0; ii < mydg; ++ii) {
        int pk = sel[myo + ii];
        int s2 = pk & 0xFFFF, e2 = pk >> 16;
        f32x2 ep = *(const f32x2*)&ehl[e2*2];
        const float* xr = &xl[s2*XSTR + d0];
        float4 xa = *(const float4*)(xr);
        float4 xb = *(const float4*)(xr + 4);
        pp0 += ep * xa.x; pp1 += ep * xa.y; pp2 += ep * xa.z; pp3 += ep * xa.w;
        pp4 += ep * xb.x; pp5 += ep * xb.y; pp6 += ep * xb.z; pp7 += ep * xb.w;
      }
      int4 w0, w1;
      w0.x = pk2(pp0.x, pp0.y); w0.y = pk2(pp1.x, pp1.y);
      w0.z = pk2(pp2.x, pp2.y); w0.w = pk2(pp3.x, pp3.y);
      w1.x = pk2(pp4.x, pp4.y); w1.y = pk2(pp5.x, pp5.y);
      w1.z = pk2(pp6.x, pp6.y); w1.w = pk2(pp7.x, pp7.y);
      *(int4*)(Ab + abase + (((uint)(dq*2  ) ^ r7) << 4)) = w0;
      *(int4*)(Ab + abase + (((uint)(dq*2+1) ^ r7) << 4)) = w1;
    }
    // issue next-chunk B regs (global; lands during MFMA)
    if (c < 63) {
      const unsigned short* W2 = W2bT + (size_t)o_s*8192 + (c+1)*128 + j2*16;
      br0 = *(const int4*)(W2); br1 = *(const int4*)(W2 + 8);
    }
    __syncthreads();                       // B: A/B tiles ready
    #pragma unroll
    for (int ks = 0; ks < 4; ++ks) {
      uint so = (uint)(ks*4+ql);
      bf16x8 bfr = *(const bf16x8*)(Bb + (uint)(nn*16+cc)*256u + ((so ^ (uint)((nn*16+cc)&7)) << 4));
      int rowa0 = mh*32 + cc;
      bf16x8 af0 = *(const bf16x8*)(Ab + (uint)rowa0*256u + ((so ^ (uint)(rowa0&7)) << 4));
      int rowa1 = rowa0 + 16;
      bf16x8 af1 = *(const bf16x8*)(Ab + (uint)rowa1*256u + ((so ^ (uint)(rowa1&7)) << 4));
      acc0 = __builtin_amdgcn_mfma_f32_16x16x32_bf16(af0, bfr, acc0, 0, 0, 0);
      acc1 = __builtin_amdgcn_mfma_f32_16x16x32_bf16(af1, bfr, acc1, 0, 0, 0);
    }
    // write next-chunk eh slice (readers wait at next A barrier)
    if (c < 63 && tid < 256 && sj < 100) ehl[sj*2+skl] = ereg;
  }

  // epilogue: + Q gather, write agg
  #pragma unroll
  for (int mi = 0; mi < 2; ++mi) {
    f32x4 a = mi ? acc1 : acc0;
    #pragma unroll
    for (int i2 = 0; i2 < 4; ++i2) {
      int v = mh*32 + mi*16 + ql*4 + i2;
      if (v < 50) {
        int o = nn*16 + cc;
        float val = 0.f;
        int dgv = degl[v];
        if (dgv > 0) {
          val = a[i2];
          int ov = offl[v];
          for (int ii = 0; ii < dgv; ++ii) {
            int s2 = sel[ov+ii] & 0xFFFF;
            val += Q[(size_t)(g*50 + s2)*64 + o];
          }
        }
        agg[(size_t)(g*50 + v)*64 + o] = val;
      }
    }
  }
}

// ---------------- per-step: NNConv root + GRU cell + next-step Q (8 nodes/wave) ----------------
__global__ __launch_bounds__(256) void k_upd(float* __restrict__ outf,
    const float* __restrict__ agg, const int* __restrict__ deg,
    const float* __restrict__ rootw, const float* __restrict__ conv_b,
    const float* __restrict__ gw6, const float* __restrict__ bih, const float* __restrict__ bhh,
    const float* __restrict__ net2_b, float* __restrict__ Q) {
  int t = threadIdx.x & 63;
  int n0 = (blockIdx.x*4 + (threadIdx.x >> 6)) * 8;
  float ot[8], m[8];
  #pragma unroll
  for (int i = 0; i < 8; ++i) ot[i] = outf[(size_t)(n0+i)*64 + t];
  #pragma unroll
  for (int i = 0; i < 8; ++i) {
    int dgi = deg[n0+i];
    m[i] = agg[(size_t)(n0+i)*64 + t] * (1.f/(float)(dgi > 0 ? dgi : 1));
  }
  for (int d = 0; d < 64; ++d) {
    float w = rootw[d*64+t];
    #pragma unroll
    for (int i = 0; i < 8; ++i) m[i] += rl(ot[i], d) * w;
  }
  float cb = conv_b[t];
  #pragma unroll
  for (int i = 0; i < 8; ++i) m[i] = lrelu(m[i] + cb);
  float air[8] = {}, aiz[8] = {}, ain[8] = {}, ahr[8] = {}, ahz[8] = {}, ahn[8] = {};
  for (int d = 0; d < 64; ++d) {
    float4 w0 = *(const float4*)&gw6[(d*64+t)*8];
    float4 w1 = *(const float4*)&gw6[(d*64+t)*8 + 4];
    #pragma unroll
    for (int i = 0; i < 8; ++i) {
      float md = rl(m[i], d), hd = rl(ot[i], d);
      air[i] += md*w0.x; aiz[i] += md*w0.y; ain[i] += md*w0.z;
      ahr[i] += hd*w0.w; ahz[i] += hd*w1.x; ahn[i] += hd*w1.y;
    }
  }
  float bi0 = bih[t], bi1 = bih[64+t], bi2 = bih[128+t];
  float bh0 = bhh[t], bh1 = bhh[64+t], bh2 = bhh[128+t];
  float h[8];
  #pragma unroll
  for (int i = 0; i < 8; ++i) {
    float rg = sigm(air[i] + bi0 + ahr[i] + bh0);
    float zg = sigm(aiz[i] + bi1 + ahz[i] + bh1);
    float ng = tanhf(ain[i] + bi2 + rg*(ahn[i] + bh2));
    h[i] = (1.f - zg)*ng + zg*ot[i];
    outf[(size_t)(n0+i)*64 + t] = h[i];
  }
  float qa[8] = {};
  for (int d = 0; d < 64; ++d) {
    float qw = net2_b[d*64+t];
    #pragma unroll
    for (int i = 0; i < 8; ++i) qa[i] += rl(h[i], d) * qw;
  }
  #pragma unroll
  for (int i = 0; i < 8; ++i) Q[(size_t)(n0+i)*64 + t] = qa[i];
}

// ---------------- per-stem head ----------------
__global__ __launch_bounds__(256) void k_stem(const float* __restrict__ outf,
    const int* __restrict__ stems, const int* __restrict__ stems_batch,
    const float* __restrict__ l1T, const float* __restrict__ l1b,
    const float* __restrict__ l2T, const float* __restrict__ l2b,
    float* __restrict__ per_stem) {
  int t = threadIdx.x & 63;
  int s = blockIdx.x*4 + (threadIdx.x>>6);
  int node = stems_batch[s]*50 + stems[s];
  float sx = outf[node*64+t];
  float t1[8];
  #pragma unroll
  for (int g = 0; g < 8; ++g) t1[g] = l1b[g*64+t];
  for (int d = 0; d < 64; ++d) {
    float xd = __shfl(sx, d);
    const float* L = l1T + d*512 + t;
    #pragma unroll
    for (int g = 0; g < 8; ++g) t1[g] += xd * L[g*64];
  }
  #pragma unroll
  for (int g = 0; g < 8; ++g) t1[g] = lrelu(t1[g]);
  float a0 = l2b[t];
  float a1 = (t < 41) ? l2b[64+t] : 0.f;
  for (int g = 0; g < 8; ++g) {
    for (int d = 0; d < 64; ++d) {
      float tj = __shfl(t1[g], d);
      int j = g*64 + d;
      a0 += tj * l2T[j*105 + t];
      a1 += tj * ((t < 41) ? l2T[j*105 + 64 + t] : 0.f);
    }
  }
  per_stem[s*105 + t] = a0;
  if (t < 41) per_stem[s*105 + 64 + t] = a1;
}

// ---------------- Set2Set (3 LSTM-attention steps) + final linear ----------------
__global__ __launch_bounds__(64) void k_s2s(const float* __restrict__ outf,
    const float* __restrict__ wihT, const float* __restrict__ whhT,
    const float* __restrict__ bih, const float* __restrict__ bhh,
    const float* __restrict__ l3w, const float* __restrict__ l3b,
    float* __restrict__ sout) {
  int b = blockIdx.x, t = threadIdx.x;
  const float* og = outf + b*50*64;
  float qlo = 0.f, qhi = 0.f, hs = 0.f, cs = 0.f;
  float b0 = bih[t]+bhh[t], b1 = bih[64+t]+bhh[64+t], b2 = bih[128+t]+bhh[128+t], b3 = bih[192+t]+bhh[192+t];
  for (int it = 0; it < 3; ++it) {
    float g0 = b0, g1 = b1, g2 = b2, g3 = b3;
    for (int c = 0; c < 64; ++c) {
      float qc = __shfl(qlo, c);
      const float* L = wihT + c*256 + t;
      g0 += qc*L[0]; g1 += qc*L[64]; g2 += qc*L[128]; g3 += qc*L[192];
    }
    for (int c = 0; c < 64; ++c) {
      float qc = __shfl(qhi, c);
      const float* L = wihT + (64+c)*256 + t;
      g0 += qc*L[0]; g1 += qc*L[64]; g2 += qc*L[128]; g3 += qc*L[192];
    }
    for (int d = 0; d < 64; ++d) {
      float hd = __shfl(hs, d);
      const float* L = whhT + d*256 + t;
      g0 += hd*L[0]; g1 += hd*L[64]; g2 += hd*L[128]; g3 += hd*L[192];
    }
    float ig = sigm(g0), fg = sigm(g1), cg = tanhf(g2), oo = sigm(g3);
    cs = fg*cs + ig*cg;
    hs = oo*tanhf(cs);
    float ei = -3.4e38f;
    for (int i = 0; i < 50; ++i) {
      float p = og[i*64+t]*hs;
      #pragma unroll
      for (int m2 = 1; m2 < 64; m2 <<= 1) p += __shfl_xor(p, m2);
      if (t == i) ei = p;
    }
    float em = ei;
    #pragma unroll
    for (int m2 = 1; m2 < 64; m2 <<= 1) em = fmaxf(em, __shfl_xor(em, m2));
    float av = (t < 50) ? __expf(ei - em) : 0.f;
    float as = av;
    #pragma unroll
    for (int m2 = 1; m2 < 64; m2 <<= 1) as += __shfl_xor(as, m2);
    av /= as;
    float rr = 0.f;
    for (int i = 0; i < 50; ++i) rr += __shfl(av, i) * og[i*64+t];
    qlo = hs; qhi = rr;
  }
  float p = qlo*l3w[t] + qhi*l3w[64+t];
  #pragma unroll
  for (int m2 = 1; m2 < 64; m2 <<= 1) p += __shfl_xor(p, m2);
  if (t == 0) sout[b] = p + l3b[0];
}

extern "C" void kernel_launch(void* const* d_in, const int* in_sizes, int n_in,
                              void* d_out, int out_size, void* d_ws, size_t ws_size,
                              hipStream_t stream) {
  const float* x          = (const float*)d_in[0];
  const float* edge_attr  = (const float*)d_in[1];
  const int*   edge_index = (const int*)  d_in[2];
  const int*   stems      = (const int*)  d_in[4];
  const int*   stems_b    = (const int*)  d_in[5];
  const float* lin0_w = (const float*)d_in[6];
  const float* lin0_b = (const float*)d_in[7];
  const float* net1_w = (const float*)d_in[8];
  const float* net1_b = (const float*)d_in[9];
  const float* net2_w = (const float*)d_in[10];
  const float* net2_b = (const float*)d_in[11];
  const float* root_w = (const float*)d_in[12];
  const float* conv_b = (const float*)d_in[13];
  const float* gru_wih = (const float*)d_in[14];
  const float* gru_whh = (const float*)d_in[15];
  const float* gru_bih = (const float*)d_in[16];
  const float* gru_bhh = (const float*)d_in[17];
  const float* lin1_w = (const float*)d_in[18];
  const float* lin1_b = (const float*)d_in[19];
  const float* lin2_w = (const float*)d_in[20];
  const float* lin2_b = (const float*)d_in[21];
  const float* lstm_wih = (const float*)d_in[22];
  const float* lstm_whh = (const float*)d_in[23];
  const float* lstm_bih = (const float*)d_in[24];
  const float* lstm_bhh = (const float*)d_in[25];
  const float* lin3_w = (const float*)d_in[26];
  const float* lin3_b = (const float*)d_in[27];

  char* ws = (char*)d_ws;
  size_t off = 0;
  auto alloc = [&](size_t bytes) { void* p = ws + off; off += (bytes + 255) & ~(size_t)255; return p; };
  float* ehT  = (float*)alloc((size_t)N_EDGES*128*4);          // 26.2MB  [k][e]
  unsigned short* W2bT = (unsigned short*)alloc(524288*2);     // 1MB
  float* outf = (float*)alloc((size_t)N_NODES*64*4);
  float* agg  = (float*)alloc((size_t)N_NODES*64*4);
  float* Qb   = (float*)alloc((size_t)N_NODES*64*4);
  int* deg  = (int*)alloc(N_NODES*4);
  int* offs = (int*)alloc(N_NODES*4);
  int* csr  = (int*)alloc(N_EDGES*4);
  float* gw6   = (float*)alloc(32768*4);
  float* lwihT = (float*)alloc(32768*4);
  float* lwhhT = (float*)alloc(16384*4);
  float* l1T   = (float*)alloc(32768*4);
  float* l2T   = (float*)alloc(53760*4);
  float* l0T   = (float*)alloc(1536*4);

  if (off > ws_size) {   // diagnosable fallback (signature absmax 1.5625e-1)
    hipMemsetAsync(d_out, 0, (size_t)out_size * sizeof(float), stream);
    return;
  }

  float* per_stem = (float*)d_out;
  float* sout = per_stem + 2560*105;

  k_prep<<<2712, 256, 0, stream>>>(net2_w, W2bT, gru_wih, gru_whh, gw6,
                                   lstm_wih, lstm_whh, lwihT, lwhhT,
                                   lin1_w, l1T, lin2_w, l2T, lin0_w, l0T);
  k_lin0<<<N_NODES/4, 256, 0, stream>>>(x, l0T, lin0_b, net2_b, outf, Qb);
  k_eh<<<N_EDGES/64, 256, 0, stream>>>(edge_attr, net1_w, net1_b, ehT);
  k_csr<<<NG, 128, 0, stream>>>(edge_index, deg, offs, csr);
  for (int s = 0; s < 12; ++s) {
    k_bilin<<<NG, 512, 0, stream>>>(outf, ehT, W2bT, Qb, edge_index, csr, offs, deg, agg);
    k_upd<<<N_NODES/32, 256, 0, stream>>>(outf, agg, deg, root_w, conv_b,
                                          gw6, gru_bih, gru_bhh, net2_b, Qb);
  }
  k_stem<<<2560/4, 256, 0, stream>>>(outf, stems, stems_b, l1T, lin1_b, l2T, lin2_b, per_stem);
  k_s2s<<<NG, 64, 0, stream>>>(outf, lwihT, lwhhT, lstm_bih, lstm_bhh, lin3_w, lin3_b, sout);
}